// Round 8
// baseline (3277.213 us; speedup 1.0000x reference)
//
#include <hip/hip_runtime.h>

#define T_STEPS 256
#define BATCH   256
#define DIN     1024
#define DH      1024

typedef _Float16 half8_t  __attribute__((ext_vector_type(8)));
typedef _Float16 half4_t  __attribute__((ext_vector_type(4)));
typedef float    f32x4_t  __attribute__((ext_vector_type(4)));
typedef float    f32x16_t __attribute__((ext_vector_type(16)));

// aux/cpol bits on gfx950: bit0 = sc0, bit4 = sc1 -> 17 = system-scope bypass
#define CPOL_SYS 17

union H4U { half4_t h; unsigned long long u; };

// Fast tanh: 1 - 2/(exp2(2*log2e*x)+1); error ~1e-7 << fp16 h quantization.
__device__ __forceinline__ float ftanh(float x) {
    float t = x * 2.885390081777927f;   // 2*log2(e)
    float e = exp2f(t);
    float r = __builtin_amdgcn_rcpf(e + 1.0f);
    return 1.0f - 2.0f * r;
}

// ---------------------------------------------------------------------------
// Split W (1024 x 2048 fp32) into Wh = W[:, :1024] and Wx = W[:, 1024:], fp16.
// ---------------------------------------------------------------------------
__global__ __launch_bounds__(256) void cvt_w(const float* __restrict__ W,
                                             _Float16* __restrict__ Wh,
                                             _Float16* __restrict__ Wx) {
    const int part = blockIdx.x >> 9;                         // 0: Wh, 1: Wx
    size_t base = ((size_t)(blockIdx.x & 511) * 256 + threadIdx.x) * 8;
    const int n = (int)(base >> 10);
    const int k = (int)(base & 1023);
    const float4* s = reinterpret_cast<const float4*>(W + (size_t)n * 2048 + part * 1024 + k);
    float4 a = s[0], b = s[1];
    half8_t h;
    h[0] = (_Float16)a.x; h[1] = (_Float16)a.y;
    h[2] = (_Float16)a.z; h[3] = (_Float16)a.w;
    h[4] = (_Float16)b.x; h[5] = (_Float16)b.y;
    h[6] = (_Float16)b.z; h[7] = (_Float16)b.w;
    _Float16* dst = part ? Wx : Wh;
    *reinterpret_cast<half8_t*>(dst + base) = h;
}

// ---------------------------------------------------------------------------
// out[0] = zeros; block 0 zeroes the 256 sync flags with system-scope stores.
// ---------------------------------------------------------------------------
__global__ __launch_bounds__(256) void zero_h0(float* __restrict__ out,
                                               int* __restrict__ flags) {
    size_t i = (size_t)blockIdx.x * 256 + threadIdx.x;
    reinterpret_cast<float4*>(out)[i] = make_float4(0.f, 0.f, 0.f, 0.f);
    if (blockIdx.x == 0) {
#pragma unroll
        for (int j = 0; j < 16; ++j)
            __hip_atomic_store(&flags[(int)threadIdx.x * 16 + j], 0,
                               __ATOMIC_RELAXED, __HIP_MEMORY_SCOPE_SYSTEM);
    }
}

// ---------------------------------------------------------------------------
// Wave-specialized fused recurrence: h_{s+1} = tanh(Wh h_s + Wx x_s + b).
// 256 WGs x 256 thr (1/CU). Group m = bid&7 owns batch rows [m*32,m*32+32)
// (all 32 WGs of a group land on XCD m under round-robin dispatch);
// WG (m,n) owns the 32x32 output tile at cols [n*32,n*32+32).
// K=2048 split across 4 waves (512 each): waves 0-1 = Wh (h part, LDS-staged
// via IF$-coherent global_load_lds), waves 2-3 = Wx (x part, global->reg,
// computed AFTER the join barrier -> overlaps the next step's poll/stage:
// the x-part is off the inter-WG critical path entirely).
// MFMA 32x32x16 f16 (half the A-operand LDS traffic per FLOP of 16x16x32).
// One barrier/step; split-K reduce via double-buffered redL.
// Epilogue: wave 0 -> Hh (write-through) + own-vmcnt drain + flag release;
// wave 1 -> out stores. Flags/h-exchange system-scope relaxed via IF$ (the
// R4-proven cache-maintenance-free protocol).
// Fragment maps (guide-verified): A: i=lane&31, k=(lane>>5)*8+e;
// B: j=lane&31, same k; D: col=lane&31, row=(reg&3)+8*(reg>>2)+4*(lane>>5).
// ---------------------------------------------------------------------------
__global__ __launch_bounds__(256, 1) void rnn_fused(
        const _Float16* __restrict__ Wh,
        const _Float16* __restrict__ Wx,
        const float* __restrict__ bias,
        const float* __restrict__ seq,
        _Float16* __restrict__ Hh,
        int* __restrict__ flags,
        float* __restrict__ out) {
    __shared__ __align__(16) _Float16 hL[2][32][520];     // per-h-wave K-half
    __shared__ __align__(16) float    redL[2][4][32][36]; // dbuf split-K partials

    const int tid  = threadIdx.x;
    const int m    = blockIdx.x & 7;        // group (XCD m): rows m*32..+32
    const int n    = blockIdx.x >> 3;       // 0..31: cols n*32..+32
    const int wave = tid >> 6;
    const int lane = tid & 63;
    const int l31  = lane & 31;
    const int lhi  = lane >> 5;             // 0/1
    const bool hwave = (wave < 2);
    const int k0 = (wave & 1) * 512;        // this wave's K-slice base

    // Weight fragments: 32 x half8 = 128 VGPR, resident all 256 steps.
    half8_t wfrag[32];
    {
        const _Float16* Wsel = hwave ? Wh : Wx;
        const _Float16* wp = Wsel + (size_t)(n * 32 + l31) * DH + k0 + lhi * 8;
#pragma unroll
        for (int ks = 0; ks < 32; ++ks)
            wfrag[ks] = *reinterpret_cast<const half8_t*>(wp + ks * 16);
    }

    // Epilogue lane map (waves 0,1): row er, 16-col half ec.
    const int er = lane >> 1;
    const int ec = (lane & 1) * 16;
    f32x4_t bias4[4];
#pragma unroll
    for (int j = 0; j < 4; ++j)
        bias4[j] = *reinterpret_cast<const f32x4_t*>(bias + n * 32 + ec + 4 * j);

    int* myflag = flags + (m * 32 + n) * 16;

    // --- x-part: acc = Wx[k-slice] . x_s -> redL[buf][wave] (waves 2,3) ---
    auto xpart = [&](int s, int buf) {
        const float* xb = seq + ((size_t)s * BATCH + m * 32 + l31) * DIN
                              + k0 + lhi * 8;
        f32x16_t a0, a1;
#pragma unroll
        for (int i = 0; i < 16; ++i) { a0[i] = 0.f; a1[i] = 0.f; }
#pragma unroll
        for (int ks = 0; ks < 32; ks += 2) {
            float4 f0 = *reinterpret_cast<const float4*>(xb + ks * 16);
            float4 f1 = *reinterpret_cast<const float4*>(xb + ks * 16 + 4);
            float4 g0 = *reinterpret_cast<const float4*>(xb + (ks + 1) * 16);
            float4 g1 = *reinterpret_cast<const float4*>(xb + (ks + 1) * 16 + 4);
            half8_t ha, hb;
            ha[0] = (_Float16)f0.x; ha[1] = (_Float16)f0.y;
            ha[2] = (_Float16)f0.z; ha[3] = (_Float16)f0.w;
            ha[4] = (_Float16)f1.x; ha[5] = (_Float16)f1.y;
            ha[6] = (_Float16)f1.z; ha[7] = (_Float16)f1.w;
            hb[0] = (_Float16)g0.x; hb[1] = (_Float16)g0.y;
            hb[2] = (_Float16)g0.z; hb[3] = (_Float16)g0.w;
            hb[4] = (_Float16)g1.x; hb[5] = (_Float16)g1.y;
            hb[6] = (_Float16)g1.z; hb[7] = (_Float16)g1.w;
            a0 = __builtin_amdgcn_mfma_f32_32x32x16_f16(ha, wfrag[ks],     a0, 0, 0, 0);
            a1 = __builtin_amdgcn_mfma_f32_32x32x16_f16(hb, wfrag[ks + 1], a1, 0, 0, 0);
        }
#pragma unroll
        for (int reg = 0; reg < 16; ++reg) {
            const int row = (reg & 3) + 8 * (reg >> 2) + 4 * lhi;
            redL[buf][wave][row][l31] = a0[reg] + a1[reg];
        }
    };

    // --- epilogue (waves 0,1): reduce redL[buf] -> tanh -> stores ---
    auto epilogue = [&](int s, int buf) {
        f32x4_t v[4];
#pragma unroll
        for (int j = 0; j < 4; ++j) {
            f32x4_t t = *reinterpret_cast<const f32x4_t*>(&redL[buf][0][er][ec + 4 * j]);
#pragma unroll
            for (int w = 1; w < 4; ++w) {
                f32x4_t p = *reinterpret_cast<const f32x4_t*>(&redL[buf][w][er][ec + 4 * j]);
                t[0] += p[0]; t[1] += p[1]; t[2] += p[2]; t[3] += p[3];
            }
            v[j][0] = ftanh(t[0] + bias4[j][0]);
            v[j][1] = ftanh(t[1] + bias4[j][1]);
            v[j][2] = ftanh(t[2] + bias4[j][2]);
            v[j][3] = ftanh(t[3] + bias4[j][3]);
        }
        if (wave == 0) {
            // h-state (fp16, write-through to IF$) then own-drain + flag.
            _Float16* hp = Hh + ((size_t)((s + 1) & 1) * BATCH + m * 32 + er) * DH
                              + n * 32 + ec;
#pragma unroll
            for (int j = 0; j < 4; ++j) {
                H4U cv;
                cv.h[0] = (_Float16)v[j][0]; cv.h[1] = (_Float16)v[j][1];
                cv.h[2] = (_Float16)v[j][2]; cv.h[3] = (_Float16)v[j][3];
                __hip_atomic_store((unsigned long long*)(hp + 4 * j), cv.u,
                                   __ATOMIC_RELAXED, __HIP_MEMORY_SCOPE_SYSTEM);
            }
            asm volatile("s_waitcnt vmcnt(0)" ::: "memory");
            if (tid == 0)
                __hip_atomic_store(myflag, s + 1, __ATOMIC_RELAXED,
                                   __HIP_MEMORY_SCOPE_SYSTEM);
        } else {
            // fp32 history output (no ordering requirement).
            float* op = out + ((size_t)(s + 1) * BATCH + m * 32 + er) * DH
                            + n * 32 + ec;
#pragma unroll
            for (int j = 0; j < 4; ++j)
                *reinterpret_cast<float4*>(op + 4 * j) =
                    make_float4(v[j][0], v[j][1], v[j][2], v[j][3]);
        }
    };

    // ---- prologue: step 0 (h0 == 0 -> only the x part contributes) ----
    if (hwave) {
#pragma unroll
        for (int reg = 0; reg < 16; ++reg) {
            const int row = (reg & 3) + 8 * (reg >> 2) + 4 * lhi;
            redL[0][wave][row][l31] = 0.f;
        }
    } else {
        xpart(0, 0);
    }
    __syncthreads();                 // B_0
    if (hwave) epilogue(0, 0);
    else       xpart(1, 1);          // x part for s=1, overlapped

    // ---- steps 1..255 ----
    for (int s = 1; s < T_STEPS; ++s) {
        const int buf = s & 1;
        if (hwave) {
            // Poll the 32 producers of group m (system-relaxed, IF$).
            const int* f = flags + (m * 32 + l31) * 16;
            int guard = 0;
            while (__hip_atomic_load(f, __ATOMIC_RELAXED,
                                     __HIP_MEMORY_SCOPE_SYSTEM) < s) {
                if (++guard > (1 << 24)) break;   // visible wrongness, not hang
            }
            // Stage own K-half of h_s (32 x 1KB chunks), own vmcnt drain.
            const _Float16* hs = Hh + ((size_t)(s & 1) * BATCH + m * 32) * DH
                                    + k0 + lane * 8;
#pragma unroll
            for (int r = 0; r < 32; ++r) {
                __builtin_amdgcn_global_load_lds(
                    (const __attribute__((address_space(1))) void*)(hs + (size_t)r * DH),
                    (__attribute__((address_space(3))) void*)&hL[wave][r][0],
                    16, 0, CPOL_SYS);
            }
            asm volatile("s_waitcnt vmcnt(0)" ::: "memory");

            // 32 MFMAs (two chains) over this wave's K-half.
            f32x16_t a0, a1;
#pragma unroll
            for (int i = 0; i < 16; ++i) { a0[i] = 0.f; a1[i] = 0.f; }
#pragma unroll
            for (int ks = 0; ks < 32; ks += 2) {
                half8_t ha = *reinterpret_cast<const half8_t*>(
                    &hL[wave][l31][ks * 16 + lhi * 8]);
                half8_t hb = *reinterpret_cast<const half8_t*>(
                    &hL[wave][l31][(ks + 1) * 16 + lhi * 8]);
                a0 = __builtin_amdgcn_mfma_f32_32x32x16_f16(ha, wfrag[ks],     a0, 0, 0, 0);
                a1 = __builtin_amdgcn_mfma_f32_32x32x16_f16(hb, wfrag[ks + 1], a1, 0, 0, 0);
            }
#pragma unroll
            for (int reg = 0; reg < 16; ++reg) {
                const int row = (reg & 3) + 8 * (reg >> 2) + 4 * lhi;
                redL[buf][wave][row][l31] = a0[reg] + a1[reg];
            }
        }
        __syncthreads();             // B_s: join (x-waves arrived early)
        if (hwave)        epilogue(s, buf);
        else if (s < 255) xpart(s + 1, (s + 1) & 1);   // overlap next x part
    }
}

// ---------------------------------------------------------------------------
// Workspace layout (bytes):
//   [0, 2M)   Wh fp16 (1024 x 1024)
//   [2M, 4M)  Wx fp16 (1024 x 1024)
//   [4M, 5M)  Hh fp16 double buffer (2 x 256 x 1024)
//   [5M, +16K) flags int[256][16]
// ---------------------------------------------------------------------------
extern "C" void kernel_launch(void* const* d_in, const int* in_sizes, int n_in,
                              void* d_out, int out_size, void* d_ws, size_t ws_size,
                              hipStream_t stream) {
    const float* seq  = (const float*)d_in[0];   // (256, 256, 1024) fp32
    const float* W    = (const float*)d_in[1];   // (1024, 2048) fp32
    const float* bias = (const float*)d_in[2];   // (1024,) fp32
    float* out        = (float*)d_out;           // (257, 256, 1024) fp32
    _Float16* Wh      = (_Float16*)d_ws;
    _Float16* Wx      = (_Float16*)d_ws + 1024 * 1024;
    _Float16* Hh      = (_Float16*)d_ws + 2 * 1024 * 1024;
    int* flags        = (int*)((char*)d_ws + 5 * 1024 * 1024);

    hipLaunchKernelGGL(cvt_w, dim3(1024), dim3(256), 0, stream, W, Wh, Wx);
    hipLaunchKernelGGL(zero_h0, dim3(256), dim3(256), 0, stream, out, flags);
    hipLaunchKernelGGL(rnn_fused, dim3(256), dim3(256), 0, stream,
                       Wh, Wx, bias, seq, Hh, flags, out);
}

// Round 9
// 1401.708 us; speedup vs baseline: 2.3380x; 2.3380x over previous
//
#include <hip/hip_runtime.h>

#define T_STEPS 256
#define BATCH   256
#define DIN     1024
#define DH      1024

typedef _Float16 half8_t __attribute__((ext_vector_type(8)));
typedef _Float16 half4_t __attribute__((ext_vector_type(4)));
typedef float    f32x4_t __attribute__((ext_vector_type(4)));

#define LDH  1032   // padded LDS row stride (halves) for h/x slabs
#define REDW 68     // padded row stride (floats) for epilogue transpose

// aux/cpol bits on gfx950: bit0 = sc0, bit4 = sc1 -> 17 = system-scope bypass
#define CPOL_SYS 17

union H4U { half4_t h; unsigned long long u; };

#define WAITVM(N)  asm volatile("s_waitcnt vmcnt(" #N ")" ::: "memory")
#define WAITLGKM0  asm volatile("s_waitcnt lgkmcnt(0)" ::: "memory")
#define RBAR()     do { __builtin_amdgcn_s_barrier(); \
                        __builtin_amdgcn_sched_barrier(0); } while (0)

// Fast tanh: 1 - 2/(exp2(2*log2e*x)+1); error ~1e-7 << fp16 h quantization.
__device__ __forceinline__ float ftanh(float x) {
    float t = x * 2.885390081777927f;   // 2*log2(e)
    float e = exp2f(t);
    float r = __builtin_amdgcn_rcpf(e + 1.0f);
    return 1.0f - 2.0f * r;
}

// ---------------------------------------------------------------------------
// Split W (1024 x 2048 fp32) into Wh = W[:, :1024] and Wx = W[:, 1024:], fp16.
// ---------------------------------------------------------------------------
__global__ __launch_bounds__(256) void cvt_w(const float* __restrict__ W,
                                             _Float16* __restrict__ Wh,
                                             _Float16* __restrict__ Wx) {
    const int part = blockIdx.x >> 9;                         // 0: Wh, 1: Wx
    size_t base = ((size_t)(blockIdx.x & 511) * 256 + threadIdx.x) * 8;
    const int n = (int)(base >> 10);
    const int k = (int)(base & 1023);
    const float4* s = reinterpret_cast<const float4*>(W + (size_t)n * 2048 + part * 1024 + k);
    float4 a = s[0], b = s[1];
    half8_t h;
    h[0] = (_Float16)a.x; h[1] = (_Float16)a.y;
    h[2] = (_Float16)a.z; h[3] = (_Float16)a.w;
    h[4] = (_Float16)b.x; h[5] = (_Float16)b.y;
    h[6] = (_Float16)b.z; h[7] = (_Float16)b.w;
    _Float16* dst = part ? Wx : Wh;
    *reinterpret_cast<half8_t*>(dst + base) = h;
}

// ---------------------------------------------------------------------------
// out[0] = zeros; block 0 zeroes the 256 packed sync flags (4-B stride).
// ---------------------------------------------------------------------------
__global__ __launch_bounds__(256) void zero_h0(float* __restrict__ out,
                                               int* __restrict__ flags) {
    size_t i = (size_t)blockIdx.x * 256 + threadIdx.x;
    reinterpret_cast<float4*>(out)[i] = make_float4(0.f, 0.f, 0.f, 0.f);
    if (blockIdx.x == 0)
        __hip_atomic_store(&flags[(int)threadIdx.x], 0,
                           __ATOMIC_RELAXED, __HIP_MEMORY_SCOPE_SYSTEM);
}

// ---------------------------------------------------------------------------
// Fused persistent recurrence: h_{s+1} = tanh(Wh h_s + Wx x_s + b).
// R7-proven structure (group m = bid&15 -> 16 batch rows; WG (m,n) -> 64
// hidden cols; all waves symmetric; K=2048 via wfrag[64]; IF$ system-scope
// exchange) with four latency cuts:
//  - x-part MFMAs PRE-POLL (xL dbuf; cvt in post-flag zone) -> hidden in the
//    flag-wait window; h-MFMAs accumulate on the x-partials.
//  - split stage: issue hf0 chunks, hf1 chunks, xv loads; vmcnt(20)->bar->
//    MFMA half1 (K<512); vmcnt(16)->bar->MFMA half2. Counted waits are exact
//    (xv issued after staging); extras only over-wait (safe direction).
//  - out-stores deferred past the flag release (off the pre-flag drain).
//  - packed flags (one 64-B line per group poll).
// ---------------------------------------------------------------------------
__global__ __launch_bounds__(256, 1) void rnn_fused(
        const _Float16* __restrict__ Wh,
        const _Float16* __restrict__ Wx,
        const float* __restrict__ bias,
        const float* __restrict__ seq,
        _Float16* __restrict__ Hh,
        int* __restrict__ flags,
        float* __restrict__ out) {
    __shared__ __align__(16) _Float16 hL[16 * LDH];
    __shared__ __align__(16) _Float16 xL[2][16 * LDH];
    __shared__ __align__(16) float redL[16 * REDW];

    const int tid  = threadIdx.x;
    const int m    = blockIdx.x & 15;
    const int n    = blockIdx.x >> 4;
    const int wave = tid >> 6;
    const int lane = tid & 63;
    const int fr   = lane & 15;
    const int quad = lane >> 4;

    // Weight fragments: wave's 16 output cols, K = 2048 ([Wh | Wx]).
    half8_t wfrag[64];
    {
        const _Float16* wph = Wh + (size_t)(n * 64 + wave * 16 + fr) * DH + quad * 8;
        const _Float16* wpx = Wx + (size_t)(n * 64 + wave * 16 + fr) * DH + quad * 8;
#pragma unroll
        for (int ks = 0; ks < 32; ++ks) {
            wfrag[ks]      = *reinterpret_cast<const half8_t*>(wph + ks * 32);
            wfrag[32 + ks] = *reinterpret_cast<const half8_t*>(wpx + ks * 32);
        }
    }

    const int r  = tid >> 4;          // 0..15 batch row within tile
    const int c4 = (tid & 15) * 4;    // 0..60 col within tile
    const size_t orowg = (size_t)(m * 16 + r);
    int* myflag = flags + (m * 16 + n);

    // x staging map (coalesced): row xr, float-offset xc + c*64.
    const int xr = tid >> 4;
    const int xc = (tid & 15) * 4;
    const float* xbase = seq + ((size_t)m * 16 + xr) * DH + xc;

    const float4 bv4 = *reinterpret_cast<const float4*>(bias + n * 64 + c4);

    float4 xv[16];

    // ---- prologue: load x_0 -> xL[0]; h1 = tanh(Wx x_0 + b) ----
    {
#pragma unroll
        for (int c = 0; c < 16; ++c)
            xv[c] = *reinterpret_cast<const float4*>(xbase + c * 64);
#pragma unroll
        for (int c = 0; c < 16; ++c) {
            half4_t h4;
            h4[0] = (_Float16)xv[c].x; h4[1] = (_Float16)xv[c].y;
            h4[2] = (_Float16)xv[c].z; h4[3] = (_Float16)xv[c].w;
            *reinterpret_cast<half4_t*>(&xL[0][xr * LDH + xc + c * 64]) = h4;
        }
        WAITLGKM0; RBAR();

        f32x4_t acc0 = {0.f,0.f,0.f,0.f}, acc1 = {0.f,0.f,0.f,0.f};
        const _Float16* pax = &xL[0][fr * LDH + quad * 8];
#pragma unroll
        for (int ks = 0; ks < 16; ++ks) {
            half8_t a0 = *reinterpret_cast<const half8_t*>(pax + (2 * ks) * 32);
            half8_t a1 = *reinterpret_cast<const half8_t*>(pax + (2 * ks + 1) * 32);
            acc0 = __builtin_amdgcn_mfma_f32_16x16x32_f16(a0, wfrag[32 + 2 * ks],     acc0, 0, 0, 0);
            acc1 = __builtin_amdgcn_mfma_f32_16x16x32_f16(a1, wfrag[32 + 2 * ks + 1], acc1, 0, 0, 0);
        }
        f32x4_t sum = acc0 + acc1;
#pragma unroll
        for (int q = 0; q < 4; ++q)
            redL[(quad * 4 + q) * REDW + wave * 16 + fr] = sum[q];
        WAITLGKM0; RBAR();

        f32x4_t t4 = *reinterpret_cast<const f32x4_t*>(&redL[r * REDW + c4]);
        float4 v = make_float4(ftanh(t4[0] + bv4.x), ftanh(t4[1] + bv4.y),
                               ftanh(t4[2] + bv4.z), ftanh(t4[3] + bv4.w));
        H4U cv;
        cv.h[0] = (_Float16)v.x; cv.h[1] = (_Float16)v.y;
        cv.h[2] = (_Float16)v.z; cv.h[3] = (_Float16)v.w;
        __hip_atomic_store(
            (unsigned long long*)(Hh + ((size_t)BATCH + orowg) * DH + n * 64 + c4),
            cv.u, __ATOMIC_RELAXED, __HIP_MEMORY_SCOPE_SYSTEM);
        WAITVM(0); RBAR();
        if (tid == 0)
            __hip_atomic_store(myflag, 1, __ATOMIC_RELAXED, __HIP_MEMORY_SCOPE_SYSTEM);

        // post-flag zone: deferred out store, then x_1 -> xL[1].
        *reinterpret_cast<float4*>(
            out + ((size_t)BATCH + orowg) * DH + n * 64 + c4) = v;
#pragma unroll
        for (int c = 0; c < 16; ++c)
            xv[c] = *reinterpret_cast<const float4*>(
                xbase + (size_t)BATCH * DH + c * 64);
#pragma unroll
        for (int c = 0; c < 16; ++c) {
            half4_t h4;
            h4[0] = (_Float16)xv[c].x; h4[1] = (_Float16)xv[c].y;
            h4[2] = (_Float16)xv[c].z; h4[3] = (_Float16)xv[c].w;
            *reinterpret_cast<half4_t*>(&xL[1][xr * LDH + xc + c * 64]) = h4;
        }
        WAITLGKM0; RBAR();
    }

    // ---- steps 1..255 ----
    for (int s = 1; s < T_STEPS; ++s) {
        const int buf = s & 1;

        // x-part MFMAs (x_s from xL[buf]) BEFORE the poll: hidden in the
        // flag-wait window. h-MFMAs accumulate on top of these partials.
        f32x4_t acc0 = {0.f,0.f,0.f,0.f}, acc1 = {0.f,0.f,0.f,0.f};
        {
            const _Float16* pax = &xL[buf][fr * LDH + quad * 8];
#pragma unroll
            for (int ks = 0; ks < 16; ++ks) {
                half8_t a0 = *reinterpret_cast<const half8_t*>(pax + (2 * ks) * 32);
                half8_t a1 = *reinterpret_cast<const half8_t*>(pax + (2 * ks + 1) * 32);
                acc0 = __builtin_amdgcn_mfma_f32_16x16x32_f16(a0, wfrag[32 + 2 * ks],     acc0, 0, 0, 0);
                acc1 = __builtin_amdgcn_mfma_f32_16x16x32_f16(a1, wfrag[32 + 2 * ks + 1], acc1, 0, 0, 0);
            }
        }

        // Poll the 16 producers of group m (packed flags: one line).
        if (tid < 16) {
            const int* f = flags + (m * 16 + tid);
            int guard = 0;
            while (__hip_atomic_load(f, __ATOMIC_RELAXED,
                                     __HIP_MEMORY_SCOPE_SYSTEM) < s) {
                if (++guard > (1 << 24)) break;   // visible wrongness, not hang
            }
        }
        RBAR();                                    // B1 (no drain needed)

        // Stage h_s: per wave 4 rows, hf0 chunks then hf1 chunks (IF$ bypass).
        const _Float16* hsrc = Hh + ((size_t)buf * BATCH + (size_t)m * 16) * DH;
#pragma unroll
        for (int i = 0; i < 4; ++i) {
            const int row = wave * 4 + i;
            __builtin_amdgcn_global_load_lds(
                (const __attribute__((address_space(1))) void*)(hsrc + (size_t)row * DH + lane * 8),
                (__attribute__((address_space(3))) void*)&hL[row * LDH],
                16, 0, CPOL_SYS);
        }
#pragma unroll
        for (int i = 0; i < 4; ++i) {
            const int row = wave * 4 + i;
            __builtin_amdgcn_global_load_lds(
                (const __attribute__((address_space(1))) void*)(hsrc + (size_t)row * DH + 512 + lane * 8),
                (__attribute__((address_space(3))) void*)&hL[row * LDH + 512],
                16, 0, CPOL_SYS);
        }
        // Issue x_{s+1} loads AFTER staging so counted vmcnt stays exact.
        {
            const int sn = (s < 255) ? s + 1 : 255;
            const float* p = xbase + (size_t)sn * (BATCH * DH);
#pragma unroll
            for (int c = 0; c < 16; ++c)
                xv[c] = *reinterpret_cast<const float4*>(p + c * 64);
        }

        WAITVM(20);                                // own hf0 (oldest 4) done
        RBAR();                                    // B2a: all waves' hf0 in LDS
        const _Float16* pah = &hL[fr * LDH + quad * 8];
#pragma unroll
        for (int ks = 0; ks < 8; ++ks) {           // K in [0, 512)
            half8_t a0 = *reinterpret_cast<const half8_t*>(pah + (2 * ks) * 32);
            half8_t a1 = *reinterpret_cast<const half8_t*>(pah + (2 * ks + 1) * 32);
            acc0 = __builtin_amdgcn_mfma_f32_16x16x32_f16(a0, wfrag[2 * ks],     acc0, 0, 0, 0);
            acc1 = __builtin_amdgcn_mfma_f32_16x16x32_f16(a1, wfrag[2 * ks + 1], acc1, 0, 0, 0);
        }
        WAITVM(16);                                // hf1 done (xv16 outstanding)
        RBAR();                                    // B2b
#pragma unroll
        for (int ks = 8; ks < 16; ++ks) {          // K in [512, 1024)
            half8_t a0 = *reinterpret_cast<const half8_t*>(pah + (2 * ks) * 32);
            half8_t a1 = *reinterpret_cast<const half8_t*>(pah + (2 * ks + 1) * 32);
            acc0 = __builtin_amdgcn_mfma_f32_16x16x32_f16(a0, wfrag[2 * ks],     acc0, 0, 0, 0);
            acc1 = __builtin_amdgcn_mfma_f32_16x16x32_f16(a1, wfrag[2 * ks + 1], acc1, 0, 0, 0);
        }
        f32x4_t sum = acc0 + acc1;
#pragma unroll
        for (int q = 0; q < 4; ++q)
            redL[(quad * 4 + q) * REDW + wave * 16 + fr] = sum[q];
        WAITLGKM0; RBAR();                         // B3: redL visible

        f32x4_t t4 = *reinterpret_cast<const f32x4_t*>(&redL[r * REDW + c4]);
        float4 v = make_float4(ftanh(t4[0] + bv4.x), ftanh(t4[1] + bv4.y),
                               ftanh(t4[2] + bv4.z), ftanh(t4[3] + bv4.w));
        H4U cv;
        cv.h[0] = (_Float16)v.x; cv.h[1] = (_Float16)v.y;
        cv.h[2] = (_Float16)v.z; cv.h[3] = (_Float16)v.w;
        __hip_atomic_store(
            (unsigned long long*)(Hh + ((size_t)((s + 1) & 1) * BATCH + orowg) * DH
                                  + n * 64 + c4),
            cv.u, __ATOMIC_RELAXED, __HIP_MEMORY_SCOPE_SYSTEM);
        WAITVM(0);                                 // Hh (and older) drained
        RBAR();                                    // B4
        if (tid == 0)
            __hip_atomic_store(myflag, s + 1, __ATOMIC_RELAXED,
                               __HIP_MEMORY_SCOPE_SYSTEM);

        // Post-flag zone: deferred out store + cvt x_{s+1} into xL[!buf].
        *reinterpret_cast<float4*>(
            out + ((size_t)(s + 1) * BATCH + orowg) * DH + n * 64 + c4) = v;
#pragma unroll
        for (int c = 0; c < 16; ++c) {
            half4_t h4;
            h4[0] = (_Float16)xv[c].x; h4[1] = (_Float16)xv[c].y;
            h4[2] = (_Float16)xv[c].z; h4[3] = (_Float16)xv[c].w;
            *reinterpret_cast<half4_t*>(&xL[buf ^ 1][xr * LDH + xc + c * 64]) = h4;
        }
        WAITLGKM0; RBAR();                         // B5: xL ready for next step
    }
}

// ---------------------------------------------------------------------------
// Workspace layout (bytes):
//   [0, 2M)   Wh fp16 (1024 x 1024)
//   [2M, 4M)  Wx fp16 (1024 x 1024)
//   [4M, 5M)  Hh fp16 double buffer (2 x 256 x 1024)
//   [5M, +1K) flags int[256] (packed, 4-B stride)
// ---------------------------------------------------------------------------
extern "C" void kernel_launch(void* const* d_in, const int* in_sizes, int n_in,
                              void* d_out, int out_size, void* d_ws, size_t ws_size,
                              hipStream_t stream) {
    const float* seq  = (const float*)d_in[0];   // (256, 256, 1024) fp32
    const float* W    = (const float*)d_in[1];   // (1024, 2048) fp32
    const float* bias = (const float*)d_in[2];   // (1024,) fp32
    float* out        = (float*)d_out;           // (257, 256, 1024) fp32
    _Float16* Wh      = (_Float16*)d_ws;
    _Float16* Wx      = (_Float16*)d_ws + 1024 * 1024;
    _Float16* Hh      = (_Float16*)d_ws + 2 * 1024 * 1024;
    int* flags        = (int*)((char*)d_ws + 5 * 1024 * 1024);

    hipLaunchKernelGGL(cvt_w, dim3(1024), dim3(256), 0, stream, W, Wh, Wx);
    hipLaunchKernelGGL(zero_h0, dim3(256), dim3(256), 0, stream, out, flags);
    hipLaunchKernelGGL(rnn_fused, dim3(256), dim3(256), 0, stream,
                       Wh, Wx, bias, seq, Hh, flags, out);
}